// Round 14
// baseline (11746.976 us; speedup 1.0000x reference)
//
#include <hip/hip_runtime.h>
#include <stdint.h>

#define NB    64
#define NN    131072
#define NPTS  1024
#define TPB   512                  // 8 waves, 1 block/CU (proven geometry)
#define WPB   4                    // workgroups per batch
#define NWAVE (TPB / 64)
#define CHUNK (NN / WPB)           // 32768 points per wg
#define PPT   (CHUNK / TPB)        // 64 points per thread
#define RPTS  40                   // register-resident points/thread
#define LPTS  24                   // LDS-resident points/thread (147456 B)
#define RPAIR (RPTS / 2)           // 20
#define LPAIR (LPTS / 2)           // 12
#define NPAIR (PPT / 2)            // 32 pairs, 4 scan-blocks of 8

typedef float v2f __attribute__((ext_vector_type(2)));
typedef unsigned long long u64;

static __device__ __forceinline__ v2f vmin2(v2f a, v2f b) {
#if __has_builtin(__builtin_elementwise_min)
    return __builtin_elementwise_min(a, b);
#else
    v2f r; r.x = fminf(a.x, b.x); r.y = fminf(a.y, b.y); return r;
#endif
}
static __device__ __forceinline__ v2f vmax2(v2f a, v2f b) {
#if __has_builtin(__builtin_elementwise_max)
    return __builtin_elementwise_max(a, b);
#else
    v2f r; r.x = fmaxf(a.x, b.x); r.y = fmaxf(a.y, b.y); return r;
#endif
}

// ---------------- inter-wg protocol: relaxed + stamped + COLD slots ----------
// HW LESSONS: RELAXED atomics only (R4: acq/rel at agent scope = cache-
// maintenance storm, 118x). Never reuse a spin address within a launch (R5).
// Aggregate intra-wg via barrier+LDS, publish ONE record per wg (R13: wave-
// level publish = slowest-wave gating at MALL latency, +2.5us). Single-stage
// spin only (R11: two-stage = 2 serial MALL trips, +0.9us).
// PAYLOAD slot (k,rank) = 4 u64 in ONE 32B block, each word self-stamped:
//   w3 = dist_bits<<32 | (NN-1-idx)<<10 | k   (u64 max = max dist, min idx)
//   w0 = x_bits<<32 | k   w1 = y_bits<<32 | k   w2 = z_bits<<32 | k
// Lane L polls rank (L&3)'s whole block (one line fetch); 2-level butterfly
// carries key+coords -> NO post-spin P[widx] reload. Slots memset once.
// COMPUTE (R11/R12-proven): pure packed hot loop (10 v_pk insts/pair) into 4
// block-max accumulators; block-skipped equality scan; split f32-max /
// u32-min wave reduces. (R13's LDS prefetch pipeline: no VALU gain, dropped.)

template <bool PAYLOAD>
__global__ __launch_bounds__(TPB)
__attribute__((amdgpu_waves_per_eu(2, 2)))
void fps_kernel(
    const float* __restrict__ pos,
    const int*   __restrict__ start_p,
    int*         __restrict__ out,
    u64*         __restrict__ slots)
{
#pragma clang fp contract(off)
    const int wg   = blockIdx.x;
    const int xcd  = wg & 7;            // heuristic: keep a batch's 4 wgs on one XCD
    const int sl   = wg >> 3;
    const int b    = xcd * 8 + (sl >> 2);
    const int r    = sl & 3;
    const int t    = threadIdx.x;
    const int lane = t & 63;
    const int wv   = t >> 6;

    const float* __restrict__ P  = pos + (size_t)b * NN * 3;
    const float* __restrict__ Pc = P + (size_t)r * CHUNK * 3;
    u64* __restrict__ bslots = slots +
        (PAYLOAD ? (size_t)b * NPTS * WPB * 4 : (size_t)b * NPTS * WPB);

    // pair-packed LDS: coords of points (2l, 2l+1) adjacent -> ds_read_b64
    __shared__ float lx[LPAIR * TPB * 2];   // 49152 B
    __shared__ float ly[LPAIR * TPB * 2];
    __shared__ float lz[LPAIR * TPB * 2];   // 147456 B total
    __shared__ u64   wred[2][NWAVE];        // banked by k&1 (single-barrier loop)

    // ---- one-time staging: j<40 -> regs, j in [40,64) -> LDS (own-thread only) ----
    v2f rx[RPAIR], ry[RPAIR], rz[RPAIR];
#pragma unroll
    for (int p = 0; p < RPAIR; ++p) {
        const float* a = Pc + (size_t)(t + (2 * p) * TPB) * 3;
        const float* c = a + (size_t)TPB * 3;
        rx[p] = (v2f){a[0], c[0]};
        ry[p] = (v2f){a[1], c[1]};
        rz[p] = (v2f){a[2], c[2]};
    }
#pragma unroll
    for (int l = 0; l < LPAIR; ++l) {
        const float* a = Pc + (size_t)(t + (RPTS + 2 * l) * TPB) * 3;
        const float* c = a + (size_t)TPB * 3;
        const int idx = (l * TPB + t) * 2;
        lx[idx] = a[0]; lx[idx + 1] = c[0];   // same-thread RAW only: no barrier
        ly[idx] = a[1]; ly[idx + 1] = c[1];
        lz[idx] = a[2]; lz[idx + 1] = c[2];
    }

    const int start = start_p[0];
    float sx = P[(size_t)start * 3 + 0];
    float sy = P[(size_t)start * 3 + 1];
    float sz = P[(size_t)start * 3 + 2];
    if (r == 0 && t == 0) out[(size_t)b * NPTS] = start;

    v2f dist[NPAIR];
#pragma unroll
    for (int p = 0; p < NPAIR; ++p)
        dist[p] = (v2f){__builtin_inff(), __builtin_inff()};

    const unsigned bt = (unsigned)(r * CHUNK + t);

    for (int k = 1; k < NPTS; ++k) {
        const int bank = k & 1;
        const v2f s0 = (v2f){sx, sx}, s1 = (v2f){sy, sy}, s2 = (v2f){sz, sz};

        v2f vb[4];
#pragma unroll
        for (int q = 0; q < 4; ++q) vb[q] = (v2f){-1.0f, -1.0f};

        // ---- loop 1: pure packed math, no scalar argmax tracking ----
        // exact per-op rounding: (dx*dx + dy*dy) + dz*dz, contract off
#define PAIR_STEP(DP, PX, PY, PZ)                                        \
        {                                                                \
            v2f dx = (PX) - s0, dy = (PY) - s1, dz = (PZ) - s2;          \
            v2f d  = (dx * dx + dy * dy) + dz * dz;                      \
            v2f nd = vmin2(dist[DP], d);                                 \
            dist[DP] = nd;                                               \
            vb[(DP) >> 3] = vmax2(vb[(DP) >> 3], nd);                    \
        }

#pragma unroll
        for (int p = 0; p < RPAIR; ++p)
            PAIR_STEP(p, rx[p], ry[p], rz[p]);
#pragma unroll
        for (int l = 0; l < LPAIR; ++l) {
            const int idx = (l * TPB + t) * 2;
            v2f px = *reinterpret_cast<const v2f*>(&lx[idx]);   // ds_read_b64
            v2f py = *reinterpret_cast<const v2f*>(&ly[idx]);
            v2f pz = *reinterpret_cast<const v2f*>(&lz[idx]);
            PAIR_STEP(RPAIR + l, px, py, pz);
        }
#undef PAIR_STEP

        // block maxes -> wave-uniform best (float reduce, cheap)
        float m[4];
#pragma unroll
        for (int q = 0; q < 4; ++q) m[q] = fmaxf(vb[q].x, vb[q].y);
        float wbest = fmaxf(fmaxf(m[0], m[1]), fmaxf(m[2], m[3]));
#pragma unroll
        for (int o = 32; o >= 1; o >>= 1)
            wbest = fmaxf(wbest, __shfl_xor(wbest, o, 64));

        // block-skipped equality scan: recover lane-local first index
        unsigned biL = 0xFFFFFFFFu;
#pragma unroll
        for (int q = 0; q < 4; ++q) {
            if (__any(m[q] == wbest)) {
#pragma unroll
                for (int p = 8 * q; p < 8 * q + 8; ++p) {
                    if (dist[p].x == wbest)
                        biL = min(biL, bt + (unsigned)((2 * p) * TPB));
                    if (dist[p].y == wbest)
                        biL = min(biL, bt + (unsigned)((2 * p + 1) * TPB));
                }
            }
        }

        // u32 min-reduce of index across the wave (wbest already uniform)
        unsigned bw = biL;
#pragma unroll
        for (int o = 32; o >= 1; o >>= 1) {
            unsigned q = (unsigned)__shfl_xor((int)bw, o, 64);
            bw = min(bw, q);
        }

        u64 wkey;
        if (PAYLOAD)
            wkey = ((u64)__float_as_uint(wbest) << 32) |
                   ((u64)(NN - 1 - bw) << 10) | (unsigned)k;
        else
            wkey = ((u64)__float_as_uint(wbest) << 32) | (unsigned)~bw;

        if (lane == 0) wred[bank][wv] = wkey;
        __syncthreads();

        // every wave reduces the 8 wave-partials itself (no 2nd barrier)
        u64 v = wred[bank][lane & (NWAVE - 1)];
#pragma unroll
        for (int o = 1; o < NWAVE; o <<= 1) {
            u64 q = __shfl_xor(v, o, 64);
            if (q > v) v = q;
        }

        if (PAYLOAD) {
            const unsigned cwidx = NN - 1 - (unsigned)((v >> 10) & 0x1FFFFull);
            // unique owner thread of the wg-winning point publishes key+coords
            // (coords from regs/LDS select — no memory dependency)
            if (biL == cwidx) {
                const unsigned jj = (cwidx - bt) >> 9;   // TPB = 512
                float wx, wy, wz;
                if (jj < RPTS) {
                    wx = 0.f; wy = 0.f; wz = 0.f;
#pragma unroll
                    for (int p = 0; p < RPAIR; ++p) {
                        if (jj == (unsigned)(2 * p))     { wx = rx[p].x; wy = ry[p].x; wz = rz[p].x; }
                        if (jj == (unsigned)(2 * p + 1)) { wx = rx[p].y; wy = ry[p].y; wz = rz[p].y; }
                    }
                } else {
                    const int jl  = (int)jj - RPTS;
                    const int idx = ((jl >> 1) * TPB + t) * 2 + (jl & 1);
                    wx = lx[idx]; wy = ly[idx]; wz = lz[idx];
                }
                u64* sb = bslots + ((size_t)k * WPB + r) * 4;
                const u64 kk = (u64)(unsigned)k;
                __hip_atomic_store(sb + 0, ((u64)__float_as_uint(wx) << 32) | kk,
                                   __ATOMIC_RELAXED, __HIP_MEMORY_SCOPE_AGENT);
                __hip_atomic_store(sb + 1, ((u64)__float_as_uint(wy) << 32) | kk,
                                   __ATOMIC_RELAXED, __HIP_MEMORY_SCOPE_AGENT);
                __hip_atomic_store(sb + 2, ((u64)__float_as_uint(wz) << 32) | kk,
                                   __ATOMIC_RELAXED, __HIP_MEMORY_SCOPE_AGENT);
                __hip_atomic_store(sb + 3, v,
                                   __ATOMIC_RELAXED, __HIP_MEMORY_SCOPE_AGENT);
            }

            // single-stage spin: lane L polls rank (L&3)'s whole 32B block
            const u64* sp = bslots + ((size_t)k * WPB + (lane & 3)) * 4;
            u64 w0, w1, w2, w3;
            for (;;) {
                w3 = __hip_atomic_load(sp + 3, __ATOMIC_RELAXED, __HIP_MEMORY_SCOPE_AGENT);
                w0 = __hip_atomic_load(sp + 0, __ATOMIC_RELAXED, __HIP_MEMORY_SCOPE_AGENT);
                w1 = __hip_atomic_load(sp + 1, __ATOMIC_RELAXED, __HIP_MEMORY_SCOPE_AGENT);
                w2 = __hip_atomic_load(sp + 2, __ATOMIC_RELAXED, __HIP_MEMORY_SCOPE_AGENT);
                if (((unsigned)(w3 & 1023ull) == (unsigned)k) &
                    ((unsigned)w0 == (unsigned)k) &
                    ((unsigned)w1 == (unsigned)k) &
                    ((unsigned)w2 == (unsigned)k)) break;
                __builtin_amdgcn_s_sleep(1);
            }

            // 2-level butterfly carrying key + coords
#pragma unroll
            for (int o = 1; o <= 2; o <<= 1) {
                u64 q3 = __shfl_xor(w3, o, 64);
                u64 q0 = __shfl_xor(w0, o, 64);
                u64 q1 = __shfl_xor(w1, o, 64);
                u64 q2 = __shfl_xor(w2, o, 64);
                if (q3 > w3) { w3 = q3; w0 = q0; w1 = q1; w2 = q2; }
            }

            const int widx = NN - 1 - (int)((w3 >> 10) & 0x1FFFFull);
            if (r == 0 && t == 0) out[(size_t)b * NPTS + k] = widx;
            sx = __uint_as_float((unsigned)(w0 >> 32));
            sy = __uint_as_float((unsigned)(w1 >> 32));
            sz = __uint_as_float((unsigned)(w2 >> 32));
        } else {
            // ---- R12-exact fallback: 1-word slot + uniform P[widx] reload ----
            if (t == 0)
                __hip_atomic_store(&bslots[(size_t)k * WPB + r], v,
                                   __ATOMIC_RELAXED, __HIP_MEMORY_SCOPE_AGENT);
            const u64* sp = &bslots[(size_t)k * WPB + (lane & 3)];
            u64 g;
            for (;;) {
                g = __hip_atomic_load(sp, __ATOMIC_RELAXED, __HIP_MEMORY_SCOPE_AGENT);
                if (g) break;
                __builtin_amdgcn_s_sleep(1);
            }
#pragma unroll
            for (int o = 1; o <= 2; o <<= 1) {
                u64 q = __shfl_xor(g, o, 64);
                if (q > g) g = q;
            }
            const int widx = (int)~(unsigned)g;
            if (r == 0 && t == 0) out[(size_t)b * NPTS + k] = widx;
            sx = P[(size_t)widx * 3 + 0];
            sy = P[(size_t)widx * 3 + 1];
            sz = P[(size_t)widx * 3 + 2];
        }
    }
}

extern "C" void kernel_launch(void* const* d_in, const int* in_sizes, int n_in,
                              void* d_out, int out_size, void* d_ws, size_t ws_size,
                              hipStream_t stream)
{
    const float* pos     = (const float*)d_in[0];
    const int*   start_p = (const int*)d_in[1];
    int*         out     = (int*)d_out;
    u64*         slots   = (u64*)d_ws;

    const size_t needP = (size_t)NB * NPTS * WPB * 4 * sizeof(u64);  // 8 MB
    const size_t need1 = (size_t)NB * NPTS * WPB * sizeof(u64);      // 2 MB

    void* args[] = { (void*)&pos, (void*)&start_p, (void*)&out, (void*)&slots };

    if (ws_size >= needP) {
        hipMemsetAsync(d_ws, 0, needP, stream);
        hipError_t e = hipLaunchCooperativeKernel(
            (const void*)fps_kernel<true>, dim3(NB * WPB), dim3(TPB),
            args, 0, stream);
        if (e != hipSuccess)
            fps_kernel<true><<<dim3(NB * WPB), dim3(TPB), 0, stream>>>(
                pos, start_p, out, slots);
    } else {
        hipMemsetAsync(d_ws, 0, need1, stream);
        hipError_t e = hipLaunchCooperativeKernel(
            (const void*)fps_kernel<false>, dim3(NB * WPB), dim3(TPB),
            args, 0, stream);
        if (e != hipSuccess)
            fps_kernel<false><<<dim3(NB * WPB), dim3(TPB), 0, stream>>>(
                pos, start_p, out, slots);
    }
}

// Round 15
// 4574.631 us; speedup vs baseline: 2.5679x; 2.5679x over previous
//
#include <hip/hip_runtime.h>
#include <stdint.h>

#define NB    64
#define NN    131072
#define NPTS  1024
#define TPB   512                  // 8 waves, 1 block/CU (proven geometry)
#define NWAVE (TPB / 64)
#define WPB2  8                    // ranks per batch (two-batch kernel)
#define CH2   (NN / WPB2)          // 16384 points per wg per batch
#define RP2   10                   // reg pairs per batch  (20 pts)
#define LP2   6                    // LDS pairs per batch  (12 pts)
#define NPAIR2 16                  // dist pairs per batch (32 pts)
// R12 fallback geometry
#define WPB1  4
#define CH1   (NN / WPB1)
#define RPAIR1 20
#define LPAIR1 12
#define NPAIR1 32

typedef float v2f __attribute__((ext_vector_type(2)));
typedef unsigned long long u64;

static __device__ __forceinline__ v2f vmin2(v2f a, v2f b) {
#if __has_builtin(__builtin_elementwise_min)
    return __builtin_elementwise_min(a, b);
#else
    v2f r; r.x = fminf(a.x, b.x); r.y = fminf(a.y, b.y); return r;
#endif
}
static __device__ __forceinline__ v2f vmax2(v2f a, v2f b) {
#if __has_builtin(__builtin_elementwise_max)
    return __builtin_elementwise_max(a, b);
#else
    v2f r; r.x = fmaxf(a.x, b.x); r.y = fmaxf(a.y, b.y); return r;
#endif
}

// ---------------- inter-wg protocol (R12-proven, unchanged) ------------------
// One u64 slot per (batch, round k, rank): [dist_bits:32 | ~idx:32].
//   u64 max == (max dist, then min idx) == jnp.argmax first-occurrence.
//   ~idx != 0 -> nonzero is the publish flag (slots memset once per launch).
// HW LESSONS: RELAXED atomics only (R4: acq/rel agent-scope = cache-
// maintenance storm, 118x). Never reuse a spin address in-launch (R5).
// ONE polled word per rank (R8/R11/R14: every extra polled word = extra MALL
// traffic, all regressed). Aggregate intra-wg via barrier+LDS, publish one
// word per wg (R13: wave-level publish regressed).
// NEW (R15): each wg serves TWO batches; round = compute A, pub A, compute B,
// pub B, resolve A (hidden: published a full compute-phase earlier), resolve
// B (single exposed MALL wait). One exposed latency per round-pair, not two.

// per-batch compute phase: pure packed math + block-max + equality scan
static __device__ __forceinline__ void phase_compute(
    const v2f (&rx)[RP2], const v2f (&ry)[RP2], const v2f (&rz)[RP2],
    const float* __restrict__ lx, const float* __restrict__ ly,
    const float* __restrict__ lz,
    v2f (&dist)[NPAIR2],
    float sx, float sy, float sz, int t, unsigned bt,
    float& wbest_o, unsigned& bw_o)
{
#pragma clang fp contract(off)
    const v2f s0 = (v2f){sx, sx}, s1 = (v2f){sy, sy}, s2 = (v2f){sz, sz};
    v2f vb0 = (v2f){-1.0f, -1.0f}, vb1 = (v2f){-1.0f, -1.0f};

#define PSTEP(DP, PX, PY, PZ)                                            \
    {                                                                    \
        v2f dx = (PX) - s0, dy = (PY) - s1, dz = (PZ) - s2;              \
        v2f d  = (dx * dx + dy * dy) + dz * dz;                          \
        v2f nd = vmin2(dist[DP], d);                                     \
        dist[DP] = nd;                                                   \
        if ((DP) < 8) vb0 = vmax2(vb0, nd); else vb1 = vmax2(vb1, nd);   \
    }
#pragma unroll
    for (int p = 0; p < RP2; ++p)
        PSTEP(p, rx[p], ry[p], rz[p]);
#pragma unroll
    for (int l = 0; l < LP2; ++l) {
        const int idx = (l * TPB + t) * 2;
        v2f px = *reinterpret_cast<const v2f*>(&lx[idx]);   // ds_read_b64
        v2f py = *reinterpret_cast<const v2f*>(&ly[idx]);
        v2f pz = *reinterpret_cast<const v2f*>(&lz[idx]);
        PSTEP(RP2 + l, px, py, pz);
    }
#undef PSTEP

    const float m0 = fmaxf(vb0.x, vb0.y), m1 = fmaxf(vb1.x, vb1.y);
    float wbest = fmaxf(m0, m1);
#pragma unroll
    for (int o = 32; o >= 1; o >>= 1)
        wbest = fmaxf(wbest, __shfl_xor(wbest, o, 64));

    unsigned biL = 0xFFFFFFFFu;
    if (__any(m0 == wbest)) {
#pragma unroll
        for (int p = 0; p < 8; ++p) {
            if (dist[p].x == wbest) biL = min(biL, bt + (unsigned)((2 * p) * TPB));
            if (dist[p].y == wbest) biL = min(biL, bt + (unsigned)((2 * p + 1) * TPB));
        }
    }
    if (__any(m1 == wbest)) {
#pragma unroll
        for (int p = 8; p < 16; ++p) {
            if (dist[p].x == wbest) biL = min(biL, bt + (unsigned)((2 * p) * TPB));
            if (dist[p].y == wbest) biL = min(biL, bt + (unsigned)((2 * p + 1) * TPB));
        }
    }
    unsigned bw = biL;
#pragma unroll
    for (int o = 32; o >= 1; o >>= 1) {
        unsigned q = (unsigned)__shfl_xor((int)bw, o, 64);
        bw = min(bw, q);
    }
    wbest_o = wbest;
    bw_o    = bw;
}

__global__ __launch_bounds__(TPB)
__attribute__((amdgpu_waves_per_eu(2, 2)))
void fps2_kernel(
    const float* __restrict__ pos,
    const int*   __restrict__ start_p,
    int*         __restrict__ out,
    u64*         __restrict__ slots)
{
#pragma clang fp contract(off)
    const int wg   = blockIdx.x;
    const int xcd  = wg & 7;            // keep a batch's 8 ranks on one XCD
    const int s    = wg >> 3;           // 0..31
    const int g    = s >> 3;            // 0..3: batch-pair group
    const int r    = s & 7;             // rank 0..7 (same for both batches)
    const int bA   = xcd * 8 + 2 * g;
    const int bB   = bA + 1;
    const int t    = threadIdx.x;
    const int lane = t & 63;
    const int wv   = t >> 6;

    const float* __restrict__ PA  = pos + (size_t)bA * NN * 3;
    const float* __restrict__ PB  = pos + (size_t)bB * NN * 3;
    const float* __restrict__ PcA = PA + (size_t)r * CH2 * 3;
    const float* __restrict__ PcB = PB + (size_t)r * CH2 * 3;
    u64* __restrict__ slotA = slots + (size_t)bA * NPTS * WPB2;
    u64* __restrict__ slotB = slots + (size_t)bB * NPTS * WPB2;

    __shared__ float lxA[LP2 * TPB * 2], lyA[LP2 * TPB * 2], lzA[LP2 * TPB * 2];
    __shared__ float lxB[LP2 * TPB * 2], lyB[LP2 * TPB * 2], lzB[LP2 * TPB * 2];
    __shared__ u64   wredA[NWAVE], wredB[NWAVE];   // each read/write pair is
                                                   // separated by the other
                                                   // batch's barrier (WAR-safe)

    // ---- one-time staging (own-thread only; no barrier needed) ----
    v2f rxA[RP2], ryA[RP2], rzA[RP2], rxB[RP2], ryB[RP2], rzB[RP2];
#pragma unroll
    for (int p = 0; p < RP2; ++p) {
        const float* a = PcA + (size_t)(t + (2 * p) * TPB) * 3;
        const float* c = a + (size_t)TPB * 3;
        rxA[p] = (v2f){a[0], c[0]}; ryA[p] = (v2f){a[1], c[1]}; rzA[p] = (v2f){a[2], c[2]};
        const float* d = PcB + (size_t)(t + (2 * p) * TPB) * 3;
        const float* e = d + (size_t)TPB * 3;
        rxB[p] = (v2f){d[0], e[0]}; ryB[p] = (v2f){d[1], e[1]}; rzB[p] = (v2f){d[2], e[2]};
    }
#pragma unroll
    for (int l = 0; l < LP2; ++l) {
        const int idx = (l * TPB + t) * 2;
        const float* a = PcA + (size_t)(t + (2 * RP2 + 2 * l) * TPB) * 3;
        const float* c = a + (size_t)TPB * 3;
        lxA[idx] = a[0]; lxA[idx + 1] = c[0];
        lyA[idx] = a[1]; lyA[idx + 1] = c[1];
        lzA[idx] = a[2]; lzA[idx + 1] = c[2];
        const float* d = PcB + (size_t)(t + (2 * RP2 + 2 * l) * TPB) * 3;
        const float* e = d + (size_t)TPB * 3;
        lxB[idx] = d[0]; lxB[idx + 1] = e[0];
        lyB[idx] = d[1]; lyB[idx + 1] = e[1];
        lzB[idx] = d[2]; lzB[idx + 1] = e[2];
    }

    const int start = start_p[0];
    float sxA = PA[(size_t)start * 3 + 0];
    float syA = PA[(size_t)start * 3 + 1];
    float szA = PA[(size_t)start * 3 + 2];
    float sxB = PB[(size_t)start * 3 + 0];
    float syB = PB[(size_t)start * 3 + 1];
    float szB = PB[(size_t)start * 3 + 2];
    if (r == 0 && t == 0) {
        out[(size_t)bA * NPTS] = start;
        out[(size_t)bB * NPTS] = start;
    }

    v2f distA[NPAIR2], distB[NPAIR2];
#pragma unroll
    for (int p = 0; p < NPAIR2; ++p) {
        distA[p] = (v2f){__builtin_inff(), __builtin_inff()};
        distB[p] = (v2f){__builtin_inff(), __builtin_inff()};
    }

    const unsigned bt = (unsigned)(r * CH2 + t);

    for (int k = 1; k < NPTS; ++k) {
        // ================= phase A: compute + publish =================
        float wbA; unsigned bwA;
        phase_compute(rxA, ryA, rzA, lxA, lyA, lzA, distA,
                      sxA, syA, szA, t, bt, wbA, bwA);
        const u64 keyA = ((u64)__float_as_uint(wbA) << 32) | (unsigned)~bwA;
        if (lane == 0) wredA[wv] = keyA;
        __syncthreads();
        u64 vA = wredA[lane & (NWAVE - 1)];
#pragma unroll
        for (int o = 1; o < NWAVE; o <<= 1) {
            u64 q = __shfl_xor(vA, o, 64);
            if (q > vA) vA = q;
        }
        if (t == 0)
            __hip_atomic_store(&slotA[(size_t)k * WPB2 + r], vA,
                               __ATOMIC_RELAXED, __HIP_MEMORY_SCOPE_AGENT);

        // ================= phase B: compute + publish =================
        float wbB; unsigned bwB;
        phase_compute(rxB, ryB, rzB, lxB, lyB, lzB, distB,
                      sxB, syB, szB, t, bt, wbB, bwB);
        const u64 keyB = ((u64)__float_as_uint(wbB) << 32) | (unsigned)~bwB;
        if (lane == 0) wredB[wv] = keyB;
        __syncthreads();
        u64 vB = wredB[lane & (NWAVE - 1)];
#pragma unroll
        for (int o = 1; o < NWAVE; o <<= 1) {
            u64 q = __shfl_xor(vB, o, 64);
            if (q > vB) vB = q;
        }
        if (t == 0)
            __hip_atomic_store(&slotB[(size_t)k * WPB2 + r], vB,
                               __ATOMIC_RELAXED, __HIP_MEMORY_SCOPE_AGENT);

        // ===== resolve A (published one compute-phase ago -> hidden) =====
        {
            const u64* sp = &slotA[(size_t)k * WPB2 + (lane & 7)];   // one 64B line
            u64 gA;
            for (;;) {
                gA = __hip_atomic_load(sp, __ATOMIC_RELAXED, __HIP_MEMORY_SCOPE_AGENT);
                if (gA) break;
                __builtin_amdgcn_s_sleep(1);
            }
#pragma unroll
            for (int o = 1; o <= 4; o <<= 1) {
                u64 q = __shfl_xor(gA, o, 64);
                if (q > gA) gA = q;
            }
            const int widxA = (int)~(unsigned)gA;
            if (r == 0 && t == 0) out[(size_t)bA * NPTS + k] = widxA;
            sxA = PA[(size_t)widxA * 3 + 0];   // issue now; B's spin hides latency
            syA = PA[(size_t)widxA * 3 + 1];
            szA = PA[(size_t)widxA * 3 + 2];
        }

        // ===== resolve B (the one exposed MALL wait per round-pair) =====
        {
            const u64* sp = &slotB[(size_t)k * WPB2 + (lane & 7)];
            u64 gB;
            for (;;) {
                gB = __hip_atomic_load(sp, __ATOMIC_RELAXED, __HIP_MEMORY_SCOPE_AGENT);
                if (gB) break;
                __builtin_amdgcn_s_sleep(1);
            }
#pragma unroll
            for (int o = 1; o <= 4; o <<= 1) {
                u64 q = __shfl_xor(gB, o, 64);
                if (q > gB) gB = q;
            }
            const int widxB = (int)~(unsigned)gB;
            if (r == 0 && t == 0) out[(size_t)bB * NPTS + k] = widxB;
            sxB = PB[(size_t)widxB * 3 + 0];
            syB = PB[(size_t)widxB * 3 + 1];
            szB = PB[(size_t)widxB * 3 + 2];
        }
    }
}

// ---------------- R12-exact fallback (ws too small) ----------------
__global__ __launch_bounds__(TPB)
__attribute__((amdgpu_waves_per_eu(2, 2)))
void fps1_kernel(
    const float* __restrict__ pos,
    const int*   __restrict__ start_p,
    int*         __restrict__ out,
    u64*         __restrict__ slots)
{
#pragma clang fp contract(off)
    const int wg   = blockIdx.x;
    const int xcd  = wg & 7;
    const int sl   = wg >> 3;
    const int b    = xcd * 8 + (sl >> 2);
    const int r    = sl & 3;
    const int t    = threadIdx.x;
    const int lane = t & 63;
    const int wv   = t >> 6;

    const float* __restrict__ P  = pos + (size_t)b * NN * 3;
    const float* __restrict__ Pc = P + (size_t)r * CH1 * 3;
    u64* __restrict__ bslots = slots + (size_t)b * NPTS * WPB1;

    __shared__ float lx[LPAIR1 * TPB * 2];
    __shared__ float ly[LPAIR1 * TPB * 2];
    __shared__ float lz[LPAIR1 * TPB * 2];
    __shared__ u64   wred[2][NWAVE];

    v2f rx[RPAIR1], ry[RPAIR1], rz[RPAIR1];
#pragma unroll
    for (int p = 0; p < RPAIR1; ++p) {
        const float* a = Pc + (size_t)(t + (2 * p) * TPB) * 3;
        const float* c = a + (size_t)TPB * 3;
        rx[p] = (v2f){a[0], c[0]};
        ry[p] = (v2f){a[1], c[1]};
        rz[p] = (v2f){a[2], c[2]};
    }
#pragma unroll
    for (int l = 0; l < LPAIR1; ++l) {
        const float* a = Pc + (size_t)(t + (2 * RPAIR1 + 2 * l) * TPB) * 3;
        const float* c = a + (size_t)TPB * 3;
        const int idx = (l * TPB + t) * 2;
        lx[idx] = a[0]; lx[idx + 1] = c[0];
        ly[idx] = a[1]; ly[idx + 1] = c[1];
        lz[idx] = a[2]; lz[idx + 1] = c[2];
    }

    const int start = start_p[0];
    float sx = P[(size_t)start * 3 + 0];
    float sy = P[(size_t)start * 3 + 1];
    float sz = P[(size_t)start * 3 + 2];
    if (r == 0 && t == 0) out[(size_t)b * NPTS] = start;

    v2f dist[NPAIR1];
#pragma unroll
    for (int p = 0; p < NPAIR1; ++p)
        dist[p] = (v2f){__builtin_inff(), __builtin_inff()};

    const unsigned bt = (unsigned)(r * CH1 + t);

    for (int k = 1; k < NPTS; ++k) {
        const int bank = k & 1;
        const v2f s0 = (v2f){sx, sx}, s1 = (v2f){sy, sy}, s2 = (v2f){sz, sz};
        v2f vb[4];
#pragma unroll
        for (int q = 0; q < 4; ++q) vb[q] = (v2f){-1.0f, -1.0f};

#define PAIR_STEP(DP, PX, PY, PZ)                                        \
        {                                                                \
            v2f dx = (PX) - s0, dy = (PY) - s1, dz = (PZ) - s2;          \
            v2f d  = (dx * dx + dy * dy) + dz * dz;                      \
            v2f nd = vmin2(dist[DP], d);                                 \
            dist[DP] = nd;                                               \
            vb[(DP) >> 3] = vmax2(vb[(DP) >> 3], nd);                    \
        }
#pragma unroll
        for (int p = 0; p < RPAIR1; ++p)
            PAIR_STEP(p, rx[p], ry[p], rz[p]);
#pragma unroll
        for (int l = 0; l < LPAIR1; ++l) {
            const int idx = (l * TPB + t) * 2;
            v2f px = *reinterpret_cast<const v2f*>(&lx[idx]);
            v2f py = *reinterpret_cast<const v2f*>(&ly[idx]);
            v2f pz = *reinterpret_cast<const v2f*>(&lz[idx]);
            PAIR_STEP(RPAIR1 + l, px, py, pz);
        }
#undef PAIR_STEP

        float m[4];
#pragma unroll
        for (int q = 0; q < 4; ++q) m[q] = fmaxf(vb[q].x, vb[q].y);
        float wbest = fmaxf(fmaxf(m[0], m[1]), fmaxf(m[2], m[3]));
#pragma unroll
        for (int o = 32; o >= 1; o >>= 1)
            wbest = fmaxf(wbest, __shfl_xor(wbest, o, 64));

        unsigned biL = 0xFFFFFFFFu;
#pragma unroll
        for (int q = 0; q < 4; ++q) {
            if (__any(m[q] == wbest)) {
#pragma unroll
                for (int p = 8 * q; p < 8 * q + 8; ++p) {
                    if (dist[p].x == wbest)
                        biL = min(biL, bt + (unsigned)((2 * p) * TPB));
                    if (dist[p].y == wbest)
                        biL = min(biL, bt + (unsigned)((2 * p + 1) * TPB));
                }
            }
        }
        unsigned bw = biL;
#pragma unroll
        for (int o = 32; o >= 1; o >>= 1) {
            unsigned q = (unsigned)__shfl_xor((int)bw, o, 64);
            bw = min(bw, q);
        }

        const u64 wkey = ((u64)__float_as_uint(wbest) << 32) | (unsigned)~bw;
        if (lane == 0) wred[bank][wv] = wkey;
        __syncthreads();
        u64 v = wred[bank][lane & (NWAVE - 1)];
#pragma unroll
        for (int o = 1; o < NWAVE; o <<= 1) {
            u64 q = __shfl_xor(v, o, 64);
            if (q > v) v = q;
        }
        if (t == 0)
            __hip_atomic_store(&bslots[(size_t)k * WPB1 + r], v,
                               __ATOMIC_RELAXED, __HIP_MEMORY_SCOPE_AGENT);
        const u64* sp = &bslots[(size_t)k * WPB1 + (lane & 3)];
        u64 g;
        for (;;) {
            g = __hip_atomic_load(sp, __ATOMIC_RELAXED, __HIP_MEMORY_SCOPE_AGENT);
            if (g) break;
            __builtin_amdgcn_s_sleep(1);
        }
#pragma unroll
        for (int o = 1; o <= 2; o <<= 1) {
            u64 q = __shfl_xor(g, o, 64);
            if (q > g) g = q;
        }
        const int widx = (int)~(unsigned)g;
        if (r == 0 && t == 0) out[(size_t)b * NPTS + k] = widx;
        sx = P[(size_t)widx * 3 + 0];
        sy = P[(size_t)widx * 3 + 1];
        sz = P[(size_t)widx * 3 + 2];
    }
}

extern "C" void kernel_launch(void* const* d_in, const int* in_sizes, int n_in,
                              void* d_out, int out_size, void* d_ws, size_t ws_size,
                              hipStream_t stream)
{
    const float* pos     = (const float*)d_in[0];
    const int*   start_p = (const int*)d_in[1];
    int*         out     = (int*)d_out;
    u64*         slots   = (u64*)d_ws;

    const size_t need2 = (size_t)NB * NPTS * WPB2 * sizeof(u64);   // 4 MB
    const size_t need1 = (size_t)NB * NPTS * WPB1 * sizeof(u64);   // 2 MB

    void* args[] = { (void*)&pos, (void*)&start_p, (void*)&out, (void*)&slots };

    if (ws_size >= need2) {
        hipMemsetAsync(d_ws, 0, need2, stream);
        hipError_t e = hipLaunchCooperativeKernel(
            (const void*)fps2_kernel, dim3(256), dim3(TPB), args, 0, stream);
        if (e != hipSuccess)
            fps2_kernel<<<dim3(256), dim3(TPB), 0, stream>>>(
                pos, start_p, out, slots);
    } else {
        hipMemsetAsync(d_ws, 0, need1, stream);
        hipError_t e = hipLaunchCooperativeKernel(
            (const void*)fps1_kernel, dim3(256), dim3(TPB), args, 0, stream);
        if (e != hipSuccess)
            fps1_kernel<<<dim3(256), dim3(TPB), 0, stream>>>(
                pos, start_p, out, slots);
    }
}

// Round 16
// 3666.008 us; speedup vs baseline: 3.2043x; 1.2479x over previous
//
#include <hip/hip_runtime.h>
#include <stdint.h>

#define NB    64
#define NN    131072
#define NPTS  1024
#define TPB   512                  // 8 waves, 1 block/CU (proven geometry)
#define WPB   4                    // workgroups per batch
#define NWAVE (TPB / 64)
#define CHUNK (NN / WPB)           // 32768 points per wg
#define PPT   (CHUNK / TPB)        // 64 points per thread
#define RPTS  40                   // register-resident points/thread
#define LPTS  24                   // LDS-resident points/thread (147456 B)
#define RPAIR (RPTS / 2)           // 20
#define LPAIR (LPTS / 2)           // 12
#define NPAIR (PPT / 2)            // 32 pairs, 4 scan-blocks of 8

typedef float v2f __attribute__((ext_vector_type(2)));
typedef unsigned long long u64;

static __device__ __forceinline__ v2f vmin2(v2f a, v2f b) {
#if __has_builtin(__builtin_elementwise_min)
    return __builtin_elementwise_min(a, b);
#else
    v2f r; r.x = fminf(a.x, b.x); r.y = fminf(a.y, b.y); return r;
#endif
}
static __device__ __forceinline__ v2f vmax2(v2f a, v2f b) {
#if __has_builtin(__builtin_elementwise_max)
    return __builtin_elementwise_max(a, b);
#else
    v2f r; r.x = fmaxf(a.x, b.x); r.y = fmaxf(a.y, b.y); return r;
#endif
}

// ---------------- FINAL (R12-champion) design, 16-round evidence -------------
// One u64 slot per (batch, round k, rank): [dist_bits:32 | ~idx:32].
//   u64 max == (max dist, then min idx) == jnp.argmax first-occurrence.
//   ~idx != 0 -> nonzero is the publish flag (slots memset once per launch).
// HW LESSONS (all measured on MI355X):
//  - RELAXED atomics only: acq/rel at agent scope = cache-maintenance storm
//    (R4: 118x slowdown).
//  - Never reuse a spin address within a launch (R5: stale polling); per-round
//    cold slots make every poll target a fresh line from the coherence point.
//  - Exactly ONE polled word per rank (R8/R11/R14: each extra polled word is
//    extra MALL traffic and regressed); uniform L3-hot P[widx] reload is
//    cheaper than any coord-payload protocol.
//  - Aggregate intra-wg with barrier+LDS, publish one word per wg (R13:
//    wave-level barrier-free publish = slowest-wave gating at MALL latency).
//  - 4-way fan-in is the sweet spot (R7: 8-way costs ~1.3us; R15: two-batch
//    hiding forced 8-way and lost).
//  - 1 block/CU full residency beats 2 blocks/CU (state ~184 live regs can't
//    fit 128/wave at 4 waves/SIMD; scratch spill = R9 disaster).
// COMPUTE (R11/R12): pure packed hot loop (10 v_pk insts/pair) into 4
// block-max accumulators; block-skipped equality scan recovers the index;
// split f32-max / u32-min wave reduces. fp contract(off) + ascending order
// -> bit-exact match with the numpy reference (absmax 0 on every round).
// Round = ~1.7us compute + ~1.9us MALL consensus latency (structural floor;
// HBM 0.2%, no bank conflicts, VALUBusy ~48%).

__global__ __launch_bounds__(TPB)
__attribute__((amdgpu_waves_per_eu(2, 2)))
void fps_kernel(
    const float* __restrict__ pos,
    const int*   __restrict__ start_p,
    int*         __restrict__ out,
    u64*         __restrict__ slots)
{
#pragma clang fp contract(off)
    const int wg   = blockIdx.x;
    const int xcd  = wg & 7;            // heuristic: keep a batch's 4 wgs on one XCD
    const int sl   = wg >> 3;
    const int b    = xcd * 8 + (sl >> 2);
    const int r    = sl & 3;
    const int t    = threadIdx.x;
    const int lane = t & 63;
    const int wv   = t >> 6;

    const float* __restrict__ P  = pos + (size_t)b * NN * 3;
    const float* __restrict__ Pc = P + (size_t)r * CHUNK * 3;
    u64* __restrict__ bslots = slots + (size_t)b * NPTS * WPB;

    // pair-packed LDS: coords of points (2l, 2l+1) adjacent -> ds_read_b64
    __shared__ float lx[LPAIR * TPB * 2];   // 49152 B
    __shared__ float ly[LPAIR * TPB * 2];
    __shared__ float lz[LPAIR * TPB * 2];   // 147456 B total
    __shared__ u64   wred[2][NWAVE];        // banked by k&1 (single-barrier loop)

    // ---- one-time staging: j<40 -> regs, j in [40,64) -> LDS (own-thread only) ----
    v2f rx[RPAIR], ry[RPAIR], rz[RPAIR];
#pragma unroll
    for (int p = 0; p < RPAIR; ++p) {
        const float* a = Pc + (size_t)(t + (2 * p) * TPB) * 3;
        const float* c = a + (size_t)TPB * 3;
        rx[p] = (v2f){a[0], c[0]};
        ry[p] = (v2f){a[1], c[1]};
        rz[p] = (v2f){a[2], c[2]};
    }
#pragma unroll
    for (int l = 0; l < LPAIR; ++l) {
        const float* a = Pc + (size_t)(t + (RPTS + 2 * l) * TPB) * 3;
        const float* c = a + (size_t)TPB * 3;
        const int idx = (l * TPB + t) * 2;
        lx[idx] = a[0]; lx[idx + 1] = c[0];   // same-thread RAW only: no barrier
        ly[idx] = a[1]; ly[idx + 1] = c[1];
        lz[idx] = a[2]; lz[idx + 1] = c[2];
    }

    const int start = start_p[0];
    float sx = P[(size_t)start * 3 + 0];
    float sy = P[(size_t)start * 3 + 1];
    float sz = P[(size_t)start * 3 + 2];
    if (r == 0 && t == 0) out[(size_t)b * NPTS] = start;

    v2f dist[NPAIR];
#pragma unroll
    for (int p = 0; p < NPAIR; ++p)
        dist[p] = (v2f){__builtin_inff(), __builtin_inff()};

    const unsigned bt = (unsigned)(r * CHUNK + t);

    for (int k = 1; k < NPTS; ++k) {
        const int bank = k & 1;
        const v2f s0 = (v2f){sx, sx}, s1 = (v2f){sy, sy}, s2 = (v2f){sz, sz};

        v2f vb[4];
#pragma unroll
        for (int q = 0; q < 4; ++q) vb[q] = (v2f){-1.0f, -1.0f};

        // ---- loop 1: pure packed math, no scalar argmax tracking ----
        // exact per-op rounding: (dx*dx + dy*dy) + dz*dz, contract off
#define PAIR_STEP(DP, PX, PY, PZ)                                        \
        {                                                                \
            v2f dx = (PX) - s0, dy = (PY) - s1, dz = (PZ) - s2;          \
            v2f d  = (dx * dx + dy * dy) + dz * dz;                      \
            v2f nd = vmin2(dist[DP], d);                                 \
            dist[DP] = nd;                                               \
            vb[(DP) >> 3] = vmax2(vb[(DP) >> 3], nd);                    \
        }

#pragma unroll
        for (int p = 0; p < RPAIR; ++p)
            PAIR_STEP(p, rx[p], ry[p], rz[p]);
#pragma unroll
        for (int l = 0; l < LPAIR; ++l) {
            const int idx = (l * TPB + t) * 2;
            v2f px = *reinterpret_cast<const v2f*>(&lx[idx]);   // ds_read_b64
            v2f py = *reinterpret_cast<const v2f*>(&ly[idx]);
            v2f pz = *reinterpret_cast<const v2f*>(&lz[idx]);
            PAIR_STEP(RPAIR + l, px, py, pz);
        }
#undef PAIR_STEP

        // block maxes -> wave-uniform best (float reduce, cheap)
        float m[4];
#pragma unroll
        for (int q = 0; q < 4; ++q) m[q] = fmaxf(vb[q].x, vb[q].y);
        float wbest = fmaxf(fmaxf(m[0], m[1]), fmaxf(m[2], m[3]));
#pragma unroll
        for (int o = 32; o >= 1; o >>= 1)
            wbest = fmaxf(wbest, __shfl_xor(wbest, o, 64));

        // block-skipped equality scan: recover lane-local first index
        unsigned biL = 0xFFFFFFFFu;
#pragma unroll
        for (int q = 0; q < 4; ++q) {
            if (__any(m[q] == wbest)) {
#pragma unroll
                for (int p = 8 * q; p < 8 * q + 8; ++p) {
                    if (dist[p].x == wbest)
                        biL = min(biL, bt + (unsigned)((2 * p) * TPB));
                    if (dist[p].y == wbest)
                        biL = min(biL, bt + (unsigned)((2 * p + 1) * TPB));
                }
            }
        }

        // u32 min-reduce of index across the wave (wbest already uniform)
        unsigned bw = biL;
#pragma unroll
        for (int o = 32; o >= 1; o >>= 1) {
            unsigned q = (unsigned)__shfl_xor((int)bw, o, 64);
            bw = min(bw, q);
        }

        const u64 wkey = ((u64)__float_as_uint(wbest) << 32) | (unsigned)~bw;

        if (lane == 0) wred[bank][wv] = wkey;
        __syncthreads();

        // every wave reduces the 8 wave-partials itself (no 2nd barrier)
        u64 v = wred[bank][lane & (NWAVE - 1)];
#pragma unroll
        for (int o = 1; o < NWAVE; o <<= 1) {
            u64 q = __shfl_xor(v, o, 64);
            if (q > v) v = q;
        }
        if (t == 0)
            __hip_atomic_store(&bslots[(size_t)k * WPB + r], v,
                               __ATOMIC_RELAXED, __HIP_MEMORY_SCOPE_AGENT);

        // all lanes spin on rank (lane&3)'s slot — cold line, relaxed only
        const u64* sp = &bslots[(size_t)k * WPB + (lane & 3)];
        u64 g;
        for (;;) {
            g = __hip_atomic_load(sp, __ATOMIC_RELAXED, __HIP_MEMORY_SCOPE_AGENT);
            if (g) break;
            __builtin_amdgcn_s_sleep(1);
        }
#pragma unroll
        for (int o = 1; o <= 2; o <<= 1) {
            u64 q = __shfl_xor(g, o, 64);
            if (q > g) g = q;
        }
        const int widx = (int)~(unsigned)g;
        if (r == 0 && t == 0) out[(size_t)b * NPTS + k] = widx;
        // uniform address across lanes: one transaction per wave, L3-hot
        sx = P[(size_t)widx * 3 + 0];
        sy = P[(size_t)widx * 3 + 1];
        sz = P[(size_t)widx * 3 + 2];
    }
}

extern "C" void kernel_launch(void* const* d_in, const int* in_sizes, int n_in,
                              void* d_out, int out_size, void* d_ws, size_t ws_size,
                              hipStream_t stream)
{
    const float* pos     = (const float*)d_in[0];
    const int*   start_p = (const int*)d_in[1];
    int*         out     = (int*)d_out;
    u64*         slots   = (u64*)d_ws;

    // 64 batches x 1024 rounds x 4 ranks x 8 B = 2 MB; zeroed so nonzero == published
    hipMemsetAsync(d_ws, 0, (size_t)NB * NPTS * WPB * sizeof(u64), stream);

    void* args[] = { (void*)&pos, (void*)&start_p, (void*)&out, (void*)&slots };
    hipError_t e = hipLaunchCooperativeKernel((const void*)fps_kernel,
                                              dim3(NB * WPB), dim3(TPB),
                                              args, 0, stream);
    if (e != hipSuccess) {
        // 256 blocks of 512 thr = 1 block/CU: de-facto co-resident; same protocol.
        fps_kernel<<<dim3(NB * WPB), dim3(TPB), 0, stream>>>(pos, start_p, out, slots);
    }
}